// Round 3
// baseline (1184.406 us; speedup 1.0000x reference)
//
#include <hip/hip_runtime.h>
#include <hip/hip_bf16.h>

#define NT 8192
#define DM 2048
#define DH 2048
#define NE 16

typedef __attribute__((ext_vector_type(8))) short short8;
typedef __attribute__((ext_vector_type(4))) float floatx4;

__device__ __forceinline__ unsigned short f2bf(float f){
  union { float f; unsigned u; } c; c.f = f;
  unsigned r = 0x7FFFu + ((c.u >> 16) & 1u);
  return (unsigned short)((c.u + r) >> 16);
}
// pack two floats as adjacent bf16 (lo in low 16 bits)
__device__ __forceinline__ unsigned pk(float lo, float hi){
  return ((unsigned)f2bf(hi) << 16) | (unsigned)f2bf(lo);
}

// ---------------- f32 -> bf16 bulk convert ----------------
__global__ __launch_bounds__(256) void cvt_kernel(
    const float4* __restrict__ src, uint2* __restrict__ dst, int n4)
{
  int i = blockIdx.x * 256 + threadIdx.x;
  if (i < n4){
    float4 v = src[i];
    dst[i] = make_uint2(pk(v.x, v.y), pk(v.z, v.w));
  }
}

// ---------------- router: one wave per token (f32) ----------------
__global__ __launch_bounds__(64) void router_kernel(
    const float* __restrict__ x,
    const float* __restrict__ rw,
    int* __restrict__ cnt,            // [2*NE]
    int* __restrict__ tok,            // [2*NE*NT]
    float* __restrict__ gate)         // [2*NE*NT]
{
  const int t = blockIdx.x;
  const int lane = threadIdx.x;
  const float4* xr = (const float4*)(x + (size_t)t * DM);
  float4 xv[8];
  #pragma unroll
  for (int i = 0; i < 8; i++) xv[i] = xr[i*64 + lane];

  float logits[NE];
  #pragma unroll
  for (int e = 0; e < NE; e++){
    const float4* wr = (const float4*)(rw + e * DM);
    float s = 0.f;
    #pragma unroll
    for (int i = 0; i < 8; i++){
      float4 wv = wr[i*64 + lane];
      s += xv[i].x*wv.x + xv[i].y*wv.y + xv[i].z*wv.z + xv[i].w*wv.w;
    }
    #pragma unroll
    for (int o = 32; o > 0; o >>= 1) s += __shfl_xor(s, o, 64);
    logits[e] = s;
  }
  if (lane == 0){
    int i1 = 0; float v1 = logits[0];
    #pragma unroll
    for (int e = 1; e < NE; e++) if (logits[e] > v1){ v1 = logits[e]; i1 = e; }
    int i2 = -1; float v2 = -3.4e38f;
    #pragma unroll
    for (int e = 0; e < NE; e++) if (e != i1 && logits[e] > v2){ v2 = logits[e]; i2 = e; }
    float ex = __expf(v2 - v1);        // <= 1, stable
    float g1 = 1.f / (1.f + ex);
    float g2 = ex / (1.f + ex);
    int p1 = atomicAdd(&cnt[i1], 1);
    tok[i1*NT + p1] = t;  gate[i1*NT + p1] = g1;
    int p2 = atomicAdd(&cnt[NE + i2], 1);
    tok[(NE + i2)*NT + p2] = t;  gate[(NE + i2)*NT + p2] = g2;
  }
}

// ---------------- grouped GEMM per (slot, expert) ----------------
// out[t][h] (+)= g * sum_d x[t][d] * W[e][d][h]; rows gathered via tok list.
// A/B sources are f32 (cvt in staging) or pre-converted bf16, per template.
template<bool ADD, bool AF32, bool BF32>
__global__ __launch_bounds__(256) void moe_gemm(
    const float* __restrict__ xf, const unsigned short* __restrict__ xb,
    const float* __restrict__ wf, const unsigned short* __restrict__ wb,
    const int* __restrict__ cnt,
    const int* __restrict__ tok,
    const float* __restrict__ gate,
    float* __restrict__ out)
{
  constexpr int BM = 128, BN = 128, BK = 64, LDK = 72;
  const int e = blockIdx.z;
  const int count = cnt[e];
  const int m0 = blockIdx.y * BM;
  if (m0 >= count) return;
  const int n0 = blockIdx.x * BN;
  const int tid = threadIdx.x;
  const int wave = tid >> 6, lane = tid & 63;

  __shared__ __align__(16) unsigned short As[BM][LDK];  // [m][k]
  __shared__ __align__(16) unsigned short Bs[BN][LDK];  // [n(h)][k(d)]

  const int srowA = tid >> 3;   // 0..31 (x4 iters of +32 rows)
  const int kcA   = tid & 7;    // 8-elem chunk within BK
  const int hp = tid & 31;      // B: h-patch (4 h each)
  const int dp = tid >> 5;      // B: d-patch 0..7 (8 d each)

  const int* tokE = tok + e*NT;
  const float* gateE = gate + e*NT;

  int tokr[4];
  #pragma unroll
  for (int it = 0; it < 4; it++){
    int gr = m0 + srowA + it*32;
    if (gr > count - 1) gr = count - 1;   // clamp; gated off at store
    tokr[it] = tokE[gr];
  }
  const size_t ebase = (size_t)e * DM * DH;

  floatx4 acc[4][4];
  #pragma unroll
  for (int i = 0; i < 4; i++)
    #pragma unroll
    for (int j = 0; j < 4; j++) acc[i][j] = (floatx4){0.f, 0.f, 0.f, 0.f};

  uint4 ra[4];        // A prefetch (bf16 path)
  float4 raf[8];      // A prefetch (f32 path)
  unsigned rbw[16];   // B patch in packed-bf16-pair form (perm input)
  float4 rbf[8];      // B prefetch (f32 path)

  // ---- prefetch stage 0 ----
  if constexpr (AF32){
    #pragma unroll
    for (int it = 0; it < 4; it++){
      const float4* p = (const float4*)&xf[(size_t)tokr[it]*DM + kcA*8];
      raf[it*2] = p[0]; raf[it*2+1] = p[1];
    }
  } else {
    #pragma unroll
    for (int it = 0; it < 4; it++)
      ra[it] = *(const uint4*)&xb[(size_t)tokr[it]*DM + kcA*8];
  }
  if constexpr (BF32){
    #pragma unroll
    for (int r = 0; r < 8; r++)
      rbf[r] = *(const float4*)&wf[ebase + (size_t)(dp*8 + r)*DH + n0 + hp*4];
  } else {
    #pragma unroll
    for (int r = 0; r < 8; r++){
      uint2 v = *(const uint2*)&wb[ebase + (size_t)(dp*8 + r)*DH + n0 + hp*4];
      rbw[r*2] = v.x; rbw[r*2+1] = v.y;
    }
  }

  const int mB = (wave & 1) * 64, nB = (wave >> 1) * 64;
  const int lrow = lane & 15, lgrp = lane >> 4;

  constexpr int S = DM / BK;  // 32 stages
  for (int s = 0; s < S; s++){
    __syncthreads();
    // ---- stage A ----
    if constexpr (AF32){
      #pragma unroll
      for (int it = 0; it < 4; it++){
        uint4 u;
        u.x = pk(raf[it*2].x,   raf[it*2].y);
        u.y = pk(raf[it*2].z,   raf[it*2].w);
        u.z = pk(raf[it*2+1].x, raf[it*2+1].y);
        u.w = pk(raf[it*2+1].z, raf[it*2+1].w);
        *(uint4*)&As[srowA + it*32][kcA*8] = u;
      }
    } else {
      #pragma unroll
      for (int it = 0; it < 4; it++)
        *(uint4*)&As[srowA + it*32][kcA*8] = ra[it];
    }
    // ---- stage B: transpose 8d x 4h patch into Bs[n=h][k=d] ----
    if constexpr (BF32){
      #pragma unroll
      for (int r = 0; r < 8; r++){
        rbw[r*2]   = pk(rbf[r].x, rbf[r].y);
        rbw[r*2+1] = pk(rbf[r].z, rbf[r].w);
      }
    }
    #pragma unroll
    for (int j = 0; j < 4; j++){
      const unsigned sel = (j & 1) ? 0x07060302u : 0x05040100u;
      const int half = j >> 1;
      uint4 wv;
      wv.x = __builtin_amdgcn_perm(rbw[1*2+half], rbw[0*2+half], sel);
      wv.y = __builtin_amdgcn_perm(rbw[3*2+half], rbw[2*2+half], sel);
      wv.z = __builtin_amdgcn_perm(rbw[5*2+half], rbw[4*2+half], sel);
      wv.w = __builtin_amdgcn_perm(rbw[7*2+half], rbw[6*2+half], sel);
      *(uint4*)&Bs[hp*4 + j][dp*8] = wv;
    }
    __syncthreads();
    // ---- prefetch stage s+1 ----
    if (s + 1 < S){
      const int k0 = (s + 1) * BK;
      if constexpr (AF32){
        #pragma unroll
        for (int it = 0; it < 4; it++){
          const float4* p = (const float4*)&xf[(size_t)tokr[it]*DM + k0 + kcA*8];
          raf[it*2] = p[0]; raf[it*2+1] = p[1];
        }
      } else {
        #pragma unroll
        for (int it = 0; it < 4; it++)
          ra[it] = *(const uint4*)&xb[(size_t)tokr[it]*DM + k0 + kcA*8];
      }
      if constexpr (BF32){
        #pragma unroll
        for (int r = 0; r < 8; r++)
          rbf[r] = *(const float4*)&wf[ebase + (size_t)(k0 + dp*8 + r)*DH + n0 + hp*4];
      } else {
        #pragma unroll
        for (int r = 0; r < 8; r++){
          uint2 v = *(const uint2*)&wb[ebase + (size_t)(k0 + dp*8 + r)*DH + n0 + hp*4];
          rbw[r*2] = v.x; rbw[r*2+1] = v.y;
        }
      }
    }
    // ---- MFMA on stage s ----
    #pragma unroll
    for (int kk = 0; kk < 2; kk++){
      const int kof = kk*32 + lgrp*8;
      short8 af[4], bfr[4];
      #pragma unroll
      for (int i = 0; i < 4; i++) af[i]  = *(const short8*)&As[mB + i*16 + lrow][kof];
      #pragma unroll
      for (int j = 0; j < 4; j++) bfr[j] = *(const short8*)&Bs[nB + j*16 + lrow][kof];
      #pragma unroll
      for (int i = 0; i < 4; i++)
        #pragma unroll
        for (int j = 0; j < 4; j++)
          acc[i][j] = __builtin_amdgcn_mfma_f32_16x16x32_bf16(af[i], bfr[j], acc[i][j], 0, 0, 0);
    }
  }

  // ---- epilogue: C row = lgrp*4 + r, col = lrow in each 16x16 tile ----
  #pragma unroll
  for (int i = 0; i < 4; i++){
    #pragma unroll
    for (int r = 0; r < 4; r++){
      const int rloc = mB + i*16 + lgrp*4 + r;
      const int gr = m0 + rloc;
      if (gr < count){
        const int t = tokE[gr];
        const float g = gateE[gr];
        float* orow = out + (size_t)t*DH + n0 + nB;
        #pragma unroll
        for (int j = 0; j < 4; j++){
          float v = acc[i][j][r] * g;
          const int col = j*16 + lrow;
          if (ADD) v += orow[col];
          orow[col] = v;
        }
      }
    }
  }
}

extern "C" void kernel_launch(void* const* d_in, const int* in_sizes, int n_in,
                              void* d_out, int out_size, void* d_ws, size_t ws_size,
                              hipStream_t stream) {
  const float* x  = (const float*)d_in[0];
  const float* rw = (const float*)d_in[1];
  const float* w  = (const float*)d_in[2];
  float* out = (float*)d_out;

  char* ws = (char*)d_ws;
  int* cnt = (int*)ws;
  int* tok = (int*)(ws + 256);
  float* gate = (float*)(ws + 256 + (size_t)2*NE*NT*4);
  const size_t base = 256 + (size_t)4*NE*NT*4;            // 2,097,408 B
  unsigned short* xb = (unsigned short*)(ws + base);
  unsigned short* wb = (unsigned short*)(ws + base + (size_t)NT*DM*2);
  const bool useXB = ws_size >= base + (size_t)NT*DM*2;
  const bool useWB = ws_size >= base + (size_t)NT*DM*2 + (size_t)NE*DM*DH*2;

  hipMemsetAsync(cnt, 0, 2*NE*sizeof(int), stream);
  router_kernel<<<NT, 64, 0, stream>>>(x, rw, cnt, tok, gate);
  if (useXB)
    cvt_kernel<<<(NT*DM/4 + 255)/256, 256, 0, stream>>>((const float4*)x, (uint2*)xb, NT*DM/4);
  if (useWB)
    cvt_kernel<<<(NE*DM*DH/4 + 255)/256, 256, 0, stream>>>((const float4*)w, (uint2*)wb, NE*DM*DH/4);

  dim3 gg(DH/128, NT/128, NE);
  if (useWB){
    moe_gemm<false,false,false><<<gg,256,0,stream>>>(x, xb, w, wb, cnt,     tok,          gate,          out);
    moe_gemm<true ,false,false><<<gg,256,0,stream>>>(x, xb, w, wb, cnt+NE,  tok+NE*NT,    gate+NE*NT,    out);
  } else if (useXB){
    moe_gemm<false,false,true ><<<gg,256,0,stream>>>(x, xb, w, wb, cnt,     tok,          gate,          out);
    moe_gemm<true ,false,true ><<<gg,256,0,stream>>>(x, xb, w, wb, cnt+NE,  tok+NE*NT,    gate+NE*NT,    out);
  } else {
    moe_gemm<false,true ,true ><<<gg,256,0,stream>>>(x, xb, w, wb, cnt,     tok,          gate,          out);
    moe_gemm<true ,true ,true ><<<gg,256,0,stream>>>(x, xb, w, wb, cnt+NE,  tok+NE*NT,    gate+NE*NT,    out);
  }
}